// Round 2
// baseline (257.510 us; speedup 1.0000x reference)
//
#include <hip/hip_runtime.h>
#include <stdint.h>

#define BT 128
#define NN 1024
#define FF 128

typedef __attribute__((ext_vector_type(8))) short short8;
typedef __attribute__((ext_vector_type(4))) float float4v;
typedef __attribute__((ext_vector_type(4))) unsigned short ushort4v;

__device__ __forceinline__ unsigned short f2bf(float f) {
  uint32_t u = __builtin_bit_cast(uint32_t, f);
  u += 0x7FFFu + ((u >> 16) & 1u);   // RNE
  return (unsigned short)(u >> 16);
}

__device__ __forceinline__ void gload16(const void* g, void* l) {
  __builtin_amdgcn_global_load_lds(
      (const __attribute__((address_space(1))) uint32_t*)(g),
      (__attribute__((address_space(3))) uint32_t*)(l),
      16, 0, 0);
}

// ---- converts -------------------------------------------------------------

__global__ __launch_bounds__(256) void k_cvt_s(const float* __restrict__ S,
                                               unsigned short* __restrict__ Sbf) {
  int i = blockIdx.x * 256 + threadIdx.x;          // 262144 float4s
  float4v v = reinterpret_cast<const float4v*>(S)[i];
  ushort4v h;
  h[0] = f2bf(v[0]); h[1] = f2bf(v[1]); h[2] = f2bf(v[2]); h[3] = f2bf(v[3]);
  reinterpret_cast<ushort4v*>(Sbf)[i] = h;
}

// W[o][f][k] (o*512+f*4+k) -> Wk2[k][o][f]
__global__ __launch_bounds__(256) void k_cvt_w(const float* __restrict__ W,
                                               unsigned short* __restrict__ Wk2) {
  int gid = blockIdx.x * 256 + threadIdx.x;        // 65536
  int k = gid >> 14, o = (gid >> 7) & 127, f = gid & 127;
  Wk2[gid] = f2bf(W[(o * 128 + f) * 4 + k]);
}

// X fp32 [bt][n][f] -> Xbf bf16 same layout, Xt bf16 [bt][f][n]
__global__ __launch_bounds__(256) void k_cvt_x(const float* __restrict__ X,
                                               unsigned short* __restrict__ Xbf,
                                               unsigned short* __restrict__ Xt) {
  __shared__ unsigned short tile[128 * 132];       // pad -> conflict-light
  int bt = blockIdx.x >> 3;
  int n0 = (blockIdx.x & 7) << 7;
  int tid = threadIdx.x;
  size_t base = ((size_t)bt * NN + n0) * FF;
#pragma unroll
  for (int i = 0; i < 16; ++i) {
    int idx = i * 256 + tid;                       // float4 units, 0..4095
    int e = idx * 4;
    int n = e >> 7, f = e & 127;
    float4v v = reinterpret_cast<const float4v*>(X + base)[idx];
    ushort4v h;
    h[0] = f2bf(v[0]); h[1] = f2bf(v[1]); h[2] = f2bf(v[2]); h[3] = f2bf(v[3]);
    reinterpret_cast<ushort4v*>(Xbf + base)[idx] = h;
    *reinterpret_cast<ushort4v*>(&tile[n * 132 + f]) = h;
  }
  __syncthreads();
  size_t tbase = (size_t)bt * (FF * NN);
#pragma unroll
  for (int i = 0; i < 64; ++i) {
    int idx = i * 256 + tid;                       // 0..16383
    int f = idx >> 7, n = idx & 127;
    Xt[tbase + (size_t)f * NN + n0 + n] = tile[n * 132 + f];
  }
}

// ---- chain GEMM: per bt, C[f][n] = sum_m Zt_in[f][m] * S[n][m] -------------
// A lds: [128 f][64 m], B lds: [128 n][64 m]; 4 waves 2x2, 64x64 each.

template <bool WRITE_ZT>
__global__ __launch_bounds__(256) void k_chain(const unsigned short* __restrict__ Zt_in,
                                               const unsigned short* __restrict__ Sbf,
                                               unsigned short* __restrict__ Zt_out,
                                               unsigned short* __restrict__ Zn_out) {
  __shared__ unsigned short lA[128 * 64];
  __shared__ unsigned short lB[128 * 64];
  int bid = blockIdx.x;
  int bt = bid >> 3;
  int n0 = (bid & 7) << 7;
  int tid = threadIdx.x;
  int wave = tid >> 6, lane = tid & 63;
  int wr = wave >> 1, wc = wave & 1;
  int lr = lane & 15, g = lane >> 4;

  const unsigned short* gA = Zt_in + (size_t)bt * (FF * NN);  // [f][m], ld=1024
  const unsigned short* gB = Sbf + (size_t)n0 * NN;           // [n][m], ld=1024

  float4v acc[4][4];
#pragma unroll
  for (int a = 0; a < 4; ++a)
#pragma unroll
    for (int b = 0; b < 4; ++b) acc[a][b] = (float4v){0.f, 0.f, 0.f, 0.f};

  for (int kt = 0; kt < 16; ++kt) {
    int m0 = kt * 64;
#pragma unroll
    for (int i = 0; i < 4; ++i) {
      int id = i * 256 + tid;
      int row = id >> 3;
      int mc = (id & 7) << 3;
      int slot = (i * 256 + (tid & 192)) * 8;      // wave-uniform lds base (elems)
      gload16(gA + (size_t)row * NN + m0 + mc, &lA[slot]);
      gload16(gB + (size_t)row * NN + m0 + mc, &lB[slot]);
    }
    __syncthreads();                                // drains vmcnt + barrier
#pragma unroll
    for (int kk = 0; kk < 2; ++kk) {
      short8 aF[4], bF[4];
#pragma unroll
      for (int mi = 0; mi < 4; ++mi)
        aF[mi] = *reinterpret_cast<const short8*>(
            &lA[(wr * 64 + mi * 16 + lr) * 64 + kk * 32 + g * 8]);
#pragma unroll
      for (int ni = 0; ni < 4; ++ni)
        bF[ni] = *reinterpret_cast<const short8*>(
            &lB[(wc * 64 + ni * 16 + lr) * 64 + kk * 32 + g * 8]);
#pragma unroll
      for (int mi = 0; mi < 4; ++mi)
#pragma unroll
        for (int ni = 0; ni < 4; ++ni)
          acc[mi][ni] = __builtin_amdgcn_mfma_f32_16x16x32_bf16(
              aF[mi], bF[ni], acc[mi][ni], 0, 0, 0);
    }
    __syncthreads();
  }

  size_t obase = (size_t)bt * (FF * NN);
#pragma unroll
  for (int mi = 0; mi < 4; ++mi) {
#pragma unroll
    for (int ni = 0; ni < 4; ++ni) {
      int fb = wr * 64 + mi * 16 + g * 4;          // D row = f
      int nloc = n0 + wc * 64 + ni * 16 + lr;      // D col = n
      ushort4v pack;
#pragma unroll
      for (int j = 0; j < 4; ++j) {
        unsigned short h = f2bf(acc[mi][ni][j]);
        pack[j] = h;
        if constexpr (WRITE_ZT)
          Zt_out[obase + (size_t)(fb + j) * NN + nloc] = h;
      }
      *reinterpret_cast<ushort4v*>(&Zn_out[obase + (size_t)nloc * FF + fb]) = pack;
    }
  }
}

// ---- output GEMM: Y[bt][n][o] = sum_k sum_f Z_k[bt-k][n][f] * W[o][f][k] + b[o]

__global__ __launch_bounds__(256) void k_out(const unsigned short* __restrict__ Xbf,
                                             const unsigned short* __restrict__ Zn1,
                                             const unsigned short* __restrict__ Zn2,
                                             const unsigned short* __restrict__ Zn3,
                                             const unsigned short* __restrict__ Wk2,
                                             const float* __restrict__ bias,
                                             float* __restrict__ Y) {
  __shared__ unsigned short lA[128 * 64];
  __shared__ unsigned short lB[128 * 64];
  int bid = blockIdx.x;
  int bt = bid >> 3;
  int n0 = (bid & 7) << 7;
  int t = bt & 31;
  int tid = threadIdx.x;
  int wave = tid >> 6, lane = tid & 63;
  int wr = wave >> 1, wc = wave & 1;
  int lr = lane & 15, g = lane >> 4;

  const unsigned short* Zs[4] = {Xbf, Zn1, Zn2, Zn3};

  float4v acc[4][4];
#pragma unroll
  for (int a = 0; a < 4; ++a)
#pragma unroll
    for (int b = 0; b < 4; ++b) acc[a][b] = (float4v){0.f, 0.f, 0.f, 0.f};

  for (int s = 0; s < 8; ++s) {
    int k = s >> 1;
    if (t < k) break;                               // uniform per block
    int fh = (s & 1) * 64;
    const unsigned short* gA = Zs[k] + ((size_t)(bt - k) * NN + n0) * FF;  // [n][f]
    const unsigned short* gB = Wk2 + k * (FF * FF);                        // [o][f]
#pragma unroll
    for (int i = 0; i < 4; ++i) {
      int id = i * 256 + tid;
      int row = id >> 3;
      int fc = (id & 7) << 3;
      int slot = (i * 256 + (tid & 192)) * 8;
      gload16(gA + (size_t)row * FF + fh + fc, &lA[slot]);
      gload16(gB + (size_t)row * FF + fh + fc, &lB[slot]);
    }
    __syncthreads();
#pragma unroll
    for (int kk = 0; kk < 2; ++kk) {
      short8 aF[4], bF[4];
#pragma unroll
      for (int mi = 0; mi < 4; ++mi)
        aF[mi] = *reinterpret_cast<const short8*>(
            &lA[(wr * 64 + mi * 16 + lr) * 64 + kk * 32 + g * 8]);
#pragma unroll
      for (int ni = 0; ni < 4; ++ni)
        bF[ni] = *reinterpret_cast<const short8*>(
            &lB[(wc * 64 + ni * 16 + lr) * 64 + kk * 32 + g * 8]);
#pragma unroll
      for (int mi = 0; mi < 4; ++mi)
#pragma unroll
        for (int ni = 0; ni < 4; ++ni)
          acc[mi][ni] = __builtin_amdgcn_mfma_f32_16x16x32_bf16(
              aF[mi], bF[ni], acc[mi][ni], 0, 0, 0);
    }
    __syncthreads();
  }

  size_t obase = (size_t)bt * (NN * FF);
#pragma unroll
  for (int mi = 0; mi < 4; ++mi) {
#pragma unroll
    for (int ni = 0; ni < 4; ++ni) {
      int nloc = n0 + wr * 64 + mi * 16 + g * 4;    // D row = n
      int o = wc * 64 + ni * 16 + lr;               // D col = o
      float bv = bias[o];
#pragma unroll
      for (int j = 0; j < 4; ++j)
        Y[obase + (size_t)(nloc + j) * FF + o] = acc[mi][ni][j] + bv;
    }
  }
}

// ---- launch ----------------------------------------------------------------

extern "C" void kernel_launch(void* const* d_in, const int* in_sizes, int n_in,
                              void* d_out, int out_size, void* d_ws, size_t ws_size,
                              hipStream_t stream) {
  const float* X = (const float*)d_in[0];
  const float* S = (const float*)d_in[1];
  const float* W = (const float*)d_in[2];
  const float* bvec = (const float*)d_in[3];
  float* Y = (float*)d_out;

  char* ws = (char*)d_ws;
  const size_t ZB = (size_t)BT * NN * FF * sizeof(unsigned short);  // 32 MiB
  unsigned short* Xt  = (unsigned short*)(ws + 0 * ZB);
  unsigned short* Zta = (unsigned short*)(ws + 1 * ZB);
  unsigned short* Ztb = (unsigned short*)(ws + 2 * ZB);
  unsigned short* Zn1 = (unsigned short*)(ws + 3 * ZB);
  unsigned short* Zn2 = (unsigned short*)(ws + 4 * ZB);
  unsigned short* Zn3 = (unsigned short*)(ws + 5 * ZB);
  unsigned short* Xbf = (unsigned short*)(ws + 6 * ZB);
  unsigned short* Sbf = (unsigned short*)(ws + 7 * ZB);
  unsigned short* Wk2 = (unsigned short*)(ws + 7 * ZB + (size_t)2 * 1024 * 1024);

  k_cvt_s<<<dim3(1024), dim3(256), 0, stream>>>(S, Sbf);
  k_cvt_w<<<dim3(256), dim3(256), 0, stream>>>(W, Wk2);
  k_cvt_x<<<dim3(1024), dim3(256), 0, stream>>>(X, Xbf, Xt);

  k_chain<true><<<dim3(1024), dim3(256), 0, stream>>>(Xt, Sbf, Zta, Zn1);
  k_chain<true><<<dim3(1024), dim3(256), 0, stream>>>(Zta, Sbf, Ztb, Zn2);
  k_chain<false><<<dim3(1024), dim3(256), 0, stream>>>(Ztb, Sbf, nullptr, Zn3);

  k_out<<<dim3(1024), dim3(256), 0, stream>>>(Xbf, Zn1, Zn2, Zn3, Wk2, bvec, Y);
}

// Round 3
// 241.182 us; speedup vs baseline: 1.0677x; 1.0677x over previous
//
#include <hip/hip_runtime.h>
#include <stdint.h>

#define BT 128
#define NN 1024
#define FF 128

typedef __attribute__((ext_vector_type(8))) short short8;
typedef __attribute__((ext_vector_type(4))) float float4v;
typedef __attribute__((ext_vector_type(4))) unsigned short ushort4v;

__device__ __forceinline__ unsigned short f2bf(float f) {
  uint32_t u = __builtin_bit_cast(uint32_t, f);
  u += 0x7FFFu + ((u >> 16) & 1u);   // RNE
  return (unsigned short)(u >> 16);
}

__device__ __forceinline__ void gload16(const void* g, void* l) {
  __builtin_amdgcn_global_load_lds(
      (const __attribute__((address_space(1))) uint32_t*)(g),
      (__attribute__((address_space(3))) uint32_t*)(l),
      16, 0, 0);
}

// ---- S -> Sbf (row-major) + SbfT (transposed), bf16 -----------------------
__global__ __launch_bounds__(256) void k_cvt_st(const float* __restrict__ S,
                                                unsigned short* __restrict__ Sbf,
                                                unsigned short* __restrict__ SbfT) {
  __shared__ unsigned short tile[128 * 132];
  int r0 = (blockIdx.x >> 3) << 7;
  int c0 = (blockIdx.x & 7) << 7;
  int tid = threadIdx.x;
#pragma unroll
  for (int i = 0; i < 16; ++i) {
    int idx = i * 256 + tid;          // 4096 float4s
    int r = idx >> 5, cq = idx & 31;
    float4v v = reinterpret_cast<const float4v*>(S)[(size_t)(r0 + r) * 256 + (c0 >> 2) + cq];
    ushort4v h;
    h[0] = f2bf(v[0]); h[1] = f2bf(v[1]); h[2] = f2bf(v[2]); h[3] = f2bf(v[3]);
    *reinterpret_cast<ushort4v*>(&Sbf[(size_t)(r0 + r) * 1024 + c0 + cq * 4]) = h;
    *reinterpret_cast<ushort4v*>(&tile[r * 132 + cq * 4]) = h;
  }
  __syncthreads();
#pragma unroll
  for (int i = 0; i < 16; ++i) {
    int idx = i * 256 + tid;          // 4096 packs
    int c = idx >> 5, rq = idx & 31;
    ushort4v h;
#pragma unroll
    for (int j = 0; j < 4; ++j) h[j] = tile[(rq * 4 + j) * 132 + c];
    *reinterpret_cast<ushort4v*>(&SbfT[(size_t)(c0 + c) * 1024 + r0 + rq * 4]) = h;
  }
}

// W[o][f][k] -> Wk2[k][o][f]
__global__ __launch_bounds__(256) void k_cvt_w(const float* __restrict__ W,
                                               unsigned short* __restrict__ Wk2) {
  int gid = blockIdx.x * 256 + threadIdx.x;
  int k = gid >> 14, o = (gid >> 7) & 127, f = gid & 127;
  Wk2[gid] = f2bf(W[(o * 128 + f) * 4 + k]);
}

// X fp32 [bt][n][f] -> Xbf bf16 same layout, Xt bf16 [bt][f][n]
__global__ __launch_bounds__(256) void k_cvt_x(const float* __restrict__ X,
                                               unsigned short* __restrict__ Xbf,
                                               unsigned short* __restrict__ Xt) {
  __shared__ unsigned short tile[128 * 132];
  int bt = blockIdx.x >> 3;
  int n0 = (blockIdx.x & 7) << 7;
  int tid = threadIdx.x;
  size_t base = ((size_t)bt * NN + n0) * FF;
#pragma unroll
  for (int i = 0; i < 16; ++i) {
    int idx = i * 256 + tid;
    int e = idx * 4;
    int n = e >> 7, f = e & 127;
    float4v v = reinterpret_cast<const float4v*>(X + base)[idx];
    ushort4v h;
    h[0] = f2bf(v[0]); h[1] = f2bf(v[1]); h[2] = f2bf(v[2]); h[3] = f2bf(v[3]);
    reinterpret_cast<ushort4v*>(Xbf + base)[idx] = h;
    *reinterpret_cast<ushort4v*>(&tile[n * 132 + f]) = h;
  }
  __syncthreads();
  size_t tbase = (size_t)bt * (FF * NN);
#pragma unroll
  for (int i = 0; i < 64; ++i) {
    int idx = i * 256 + tid;
    int f = idx >> 7, n = idx & 127;
    Xt[tbase + (size_t)f * NN + n0 + n] = tile[n * 132 + f];
  }
}

// ---- small 1024^3 GEMM (m97 structure): C[r][c] = sum_p A[r][p]*B[c][p] ----
__global__ __launch_bounds__(256) void gemm_s(const unsigned short* __restrict__ A,
                                              const unsigned short* __restrict__ B,
                                              unsigned short* __restrict__ C) {
  __shared__ unsigned short lA[128 * 64];
  __shared__ unsigned short lB[128 * 64];
  int r0 = (blockIdx.x >> 3) << 7;
  int c0 = (blockIdx.x & 7) << 7;
  int tid = threadIdx.x;
  int wave = tid >> 6, lane = tid & 63;
  int wr = wave >> 1, wc = wave & 1;
  int lr = lane & 15, g = lane >> 4;

  const unsigned short* gA = A + (size_t)r0 * 1024;
  const unsigned short* gB = B + (size_t)c0 * 1024;

  float4v acc[4][4];
#pragma unroll
  for (int a = 0; a < 4; ++a)
#pragma unroll
    for (int b = 0; b < 4; ++b) acc[a][b] = (float4v){0.f, 0.f, 0.f, 0.f};

  for (int kt = 0; kt < 16; ++kt) {
    int m0 = kt * 64;
#pragma unroll
    for (int i = 0; i < 4; ++i) {
      int id = i * 256 + tid;
      int row = id >> 3;
      int mc = (id & 7) << 3;
      int slot = (i * 256 + (tid & 192)) * 8;
      gload16(gA + (size_t)row * 1024 + m0 + mc, &lA[slot]);
      gload16(gB + (size_t)row * 1024 + m0 + mc, &lB[slot]);
    }
    __syncthreads();
#pragma unroll
    for (int kk = 0; kk < 2; ++kk) {
      short8 aF[4], bF[4];
#pragma unroll
      for (int mi = 0; mi < 4; ++mi)
        aF[mi] = *reinterpret_cast<const short8*>(
            &lA[(wr * 64 + mi * 16 + lr) * 64 + kk * 32 + g * 8]);
#pragma unroll
      for (int ni = 0; ni < 4; ++ni)
        bF[ni] = *reinterpret_cast<const short8*>(
            &lB[(wc * 64 + ni * 16 + lr) * 64 + kk * 32 + g * 8]);
#pragma unroll
      for (int mi = 0; mi < 4; ++mi)
#pragma unroll
        for (int ni = 0; ni < 4; ++ni)
          acc[mi][ni] = __builtin_amdgcn_mfma_f32_16x16x32_bf16(
              aF[mi], bF[ni], acc[mi][ni], 0, 0, 0);
    }
    __syncthreads();
  }

#pragma unroll
  for (int mi = 0; mi < 4; ++mi) {
#pragma unroll
    for (int ni = 0; ni < 4; ++ni) {
      int rr = r0 + wr * 64 + mi * 16 + g * 4;
      int cc = c0 + wc * 64 + ni * 16 + lr;
#pragma unroll
      for (int j = 0; j < 4; ++j)
        C[(size_t)(rr + j) * 1024 + cc] = f2bf(acc[mi][ni][j]);
    }
  }
}

// ---- batched chain GEMM, 256^2 tile, 4-phase/ktile schedule ----------------
// For power k: Zn_k[bt][n][f] = sum_m Xt[(bt,f)][m] * S^k[n][m]
// A = Xt rows (c = bt*128+f, M-dim), B = S^k rows (n, N-dim), K = m (1024).
__global__ __launch_bounds__(512, 2) void k_chain8(
    const unsigned short* __restrict__ Xt,
    const unsigned short* __restrict__ S1,
    const unsigned short* __restrict__ S2,
    const unsigned short* __restrict__ S3,
    unsigned short* __restrict__ Zn1,
    unsigned short* __restrict__ Zn2,
    unsigned short* __restrict__ Zn3) {
  extern __shared__ unsigned char lds[];   // 131072 B: 2 bufs x (A 32K + B 32K)

  // XCD-chunked mapping, pk fastest: Xt panel stays on one XCD.
  int bid = blockIdx.x;
  int logical = (bid & 7) * 96 + (bid >> 3);     // 768 = 8 * 96 exact
  int cblk = logical / 12;
  int pkn = logical - cblk * 12;
  int power = pkn >> 2, nblk = pkn & 3;
  const unsigned short* Sp = (power == 0) ? S1 : ((power == 1) ? S2 : S3);
  unsigned short* Zn = (power == 0) ? Zn1 : ((power == 1) ? Zn2 : Zn3);

  int tid = threadIdx.x;
  int wave = tid >> 6, lane = tid & 63;
  int wave_m = wave >> 2, wave_n = wave & 3;
  int lr = lane & 15, g = lane >> 4;

  // staging source offsets (elements), pre-swizzled: kseg' = kseg ^ (row&7)
  unsigned asrc[4], bsrc[4];
#pragma unroll
  for (int j = 0; j < 4; ++j) {
    int slot = j * 512 + tid;
    int row = slot >> 3, kseg = slot & 7;
    asrc[j] = (unsigned)(cblk * 256 + row) * 1024u + (unsigned)((kseg ^ (row & 7)) << 3);
    bsrc[j] = (unsigned)(nblk * 256 + row) * 1024u + (unsigned)((kseg ^ (row & 7)) << 3);
  }
  unsigned stage_base = (unsigned)wave * 1024u;  // wave-uniform, + j*8192

  float4v acc[8][4];
#pragma unroll
  for (int a = 0; a < 8; ++a)
#pragma unroll
    for (int b = 0; b < 4; ++b) acc[a][b] = (float4v){0.f, 0.f, 0.f, 0.f};

  // prologue: stage ktile 0 into buf0
#pragma unroll
  for (int j = 0; j < 4; ++j) {
    gload16(Xt + asrc[j], lds + j * 8192 + stage_base);
    gload16(Sp + bsrc[j], lds + 32768 + j * 8192 + stage_base);
  }
  asm volatile("s_waitcnt vmcnt(0)" ::: "memory");
  __builtin_amdgcn_s_barrier();

  // ds_read bases (bytes), read-side swizzle on kbyte
  const int xm = (lr & 7) << 4;
  const int xo0 = (g * 16) ^ xm;
  const int xo1 = (64 + g * 16) ^ xm;
  const int arow = (wave_m * 128 + lr) * 128;
  const int brow = 32768 + (wave_n * 64 + lr) * 128;

  for (int kt = 0; kt < 16; ++kt) {
    const unsigned bo = (unsigned)(kt & 1) * 65536u;
    const unsigned nbo = bo ^ 65536u;
#pragma unroll
    for (int q = 0; q < 4; ++q) {
      const int mh = q >> 1, nh = q & 1;
      short8 aF[4][2], bF[2][2];
#pragma unroll
      for (int a = 0; a < 4; ++a) {
        const unsigned char* rb = lds + bo + arow + (mh * 4 + a) * 2048;
        aF[a][0] = *reinterpret_cast<const short8*>(rb + xo0);
        aF[a][1] = *reinterpret_cast<const short8*>(rb + xo1);
      }
#pragma unroll
      for (int b2 = 0; b2 < 2; ++b2) {
        const unsigned char* rb = lds + bo + brow + (nh * 2 + b2) * 2048;
        bF[b2][0] = *reinterpret_cast<const short8*>(rb + xo0);
        bF[b2][1] = *reinterpret_cast<const short8*>(rb + xo1);
      }
      if (q == 0 && kt < 15) {
        unsigned koff = (unsigned)(kt + 1) * 64u;
#pragma unroll
        for (int j = 0; j < 4; ++j) {
          gload16(Xt + asrc[j] + koff, lds + nbo + j * 8192 + stage_base);
          gload16(Sp + bsrc[j] + koff, lds + nbo + 32768u + j * 8192 + stage_base);
        }
      }
      if (q == 3) asm volatile("s_waitcnt vmcnt(0)" ::: "memory");
      __builtin_amdgcn_s_barrier();
      asm volatile("s_waitcnt lgkmcnt(0)" ::: "memory");
      __builtin_amdgcn_sched_barrier(0);
      __builtin_amdgcn_s_setprio(1);
#pragma unroll
      for (int a = 0; a < 4; ++a)
#pragma unroll
        for (int b2 = 0; b2 < 2; ++b2) {
          acc[mh * 4 + a][nh * 2 + b2] = __builtin_amdgcn_mfma_f32_16x16x32_bf16(
              aF[a][0], bF[b2][0], acc[mh * 4 + a][nh * 2 + b2], 0, 0, 0);
          acc[mh * 4 + a][nh * 2 + b2] = __builtin_amdgcn_mfma_f32_16x16x32_bf16(
              aF[a][1], bF[b2][1], acc[mh * 4 + a][nh * 2 + b2], 0, 0, 0);
        }
      __builtin_amdgcn_s_setprio(0);
      __builtin_amdgcn_sched_barrier(0);
      __builtin_amdgcn_s_barrier();
    }
  }

  // epilogue: frag (mf,nf): c = cblk*256 + wave_m*128 + mf*16 + g*4 + j (M/A-row)
  //                         n = nblk*256 + wave_n*64 + nf*16 + lr       (N/B-row)
  int bt = cblk * 2 + wave_m;
  int nbase = nblk * 256 + wave_n * 64 + lr;
  size_t zbase = (size_t)bt * (NN * FF);
#pragma unroll
  for (int mf = 0; mf < 8; ++mf) {
    int f0 = mf * 16 + g * 4;
#pragma unroll
    for (int nf = 0; nf < 4; ++nf) {
      int n = nbase + nf * 16;
      ushort4v pk;
#pragma unroll
      for (int j = 0; j < 4; ++j) pk[j] = f2bf(acc[mf][nf][j]);
      *reinterpret_cast<ushort4v*>(&Zn[zbase + (size_t)n * FF + f0]) = pk;
    }
  }
}

// ---- output GEMM: Y[bt][n][o] = sum_k sum_f Z_k[bt-k][n][f] * Wk2[k][o][f] + b
__global__ __launch_bounds__(256) void k_out(const unsigned short* __restrict__ Xbf,
                                             const unsigned short* __restrict__ Zn1,
                                             const unsigned short* __restrict__ Zn2,
                                             const unsigned short* __restrict__ Zn3,
                                             const unsigned short* __restrict__ Wk2,
                                             const float* __restrict__ bias,
                                             float* __restrict__ Y) {
  __shared__ unsigned short lA[128 * 64];
  __shared__ unsigned short lB[128 * 64];
  int bid = blockIdx.x;
  int bt = bid >> 3;
  int n0 = (bid & 7) << 7;
  int t = bt & 31;
  int tid = threadIdx.x;
  int wave = tid >> 6, lane = tid & 63;
  int wr = wave >> 1, wc = wave & 1;
  int lr = lane & 15, g = lane >> 4;

  const unsigned short* Zs[4] = {Xbf, Zn1, Zn2, Zn3};

  float4v acc[4][4];
#pragma unroll
  for (int a = 0; a < 4; ++a)
#pragma unroll
    for (int b = 0; b < 4; ++b) acc[a][b] = (float4v){0.f, 0.f, 0.f, 0.f};

  for (int s = 0; s < 8; ++s) {
    int k = s >> 1;
    if (t < k) break;
    int fh = (s & 1) * 64;
    const unsigned short* gA = Zs[k] + ((size_t)(bt - k) * NN + n0) * FF;
    const unsigned short* gB = Wk2 + k * (FF * FF);
#pragma unroll
    for (int i = 0; i < 4; ++i) {
      int id = i * 256 + tid;
      int row = id >> 3;
      int fc = (id & 7) << 3;
      int slot = (i * 256 + (tid & 192)) * 8;
      gload16(gA + (size_t)row * FF + fh + fc, &lA[slot]);
      gload16(gB + (size_t)row * FF + fh + fc, &lB[slot]);
    }
    __syncthreads();
#pragma unroll
    for (int kk = 0; kk < 2; ++kk) {
      short8 aF[4], bF[4];
#pragma unroll
      for (int mi = 0; mi < 4; ++mi)
        aF[mi] = *reinterpret_cast<const short8*>(
            &lA[(wr * 64 + mi * 16 + lr) * 64 + kk * 32 + g * 8]);
#pragma unroll
      for (int ni = 0; ni < 4; ++ni)
        bF[ni] = *reinterpret_cast<const short8*>(
            &lB[(wc * 64 + ni * 16 + lr) * 64 + kk * 32 + g * 8]);
#pragma unroll
      for (int mi = 0; mi < 4; ++mi)
#pragma unroll
        for (int ni = 0; ni < 4; ++ni)
          acc[mi][ni] = __builtin_amdgcn_mfma_f32_16x16x32_bf16(
              aF[mi], bF[ni], acc[mi][ni], 0, 0, 0);
    }
    __syncthreads();
  }

  size_t obase = (size_t)bt * (NN * FF);
#pragma unroll
  for (int mi = 0; mi < 4; ++mi) {
#pragma unroll
    for (int ni = 0; ni < 4; ++ni) {
      int nloc = n0 + wr * 64 + mi * 16 + g * 4;
      int o = wc * 64 + ni * 16 + lr;
      float bv = bias[o];
#pragma unroll
      for (int j = 0; j < 4; ++j)
        Y[obase + (size_t)(nloc + j) * FF + o] = acc[mi][ni][j] + bv;
    }
  }
}

// ---- launch ----------------------------------------------------------------

extern "C" void kernel_launch(void* const* d_in, const int* in_sizes, int n_in,
                              void* d_out, int out_size, void* d_ws, size_t ws_size,
                              hipStream_t stream) {
  const float* X = (const float*)d_in[0];
  const float* S = (const float*)d_in[1];
  const float* W = (const float*)d_in[2];
  const float* bvec = (const float*)d_in[3];
  float* Y = (float*)d_out;

  char* ws = (char*)d_ws;
  const size_t ZB = (size_t)BT * NN * FF * sizeof(unsigned short);  // 32 MiB
  const size_t SB = (size_t)1024 * 1024 * sizeof(unsigned short);   // 2 MiB
  unsigned short* Xt   = (unsigned short*)(ws + 0 * ZB);
  unsigned short* Zn1  = (unsigned short*)(ws + 1 * ZB);
  unsigned short* Zn2  = (unsigned short*)(ws + 2 * ZB);
  unsigned short* Zn3  = (unsigned short*)(ws + 3 * ZB);
  unsigned short* Xbf  = (unsigned short*)(ws + 4 * ZB);
  unsigned short* Sbf  = (unsigned short*)(ws + 5 * ZB);
  unsigned short* SbfT = (unsigned short*)(ws + 5 * ZB + 1 * SB);
  unsigned short* S2   = (unsigned short*)(ws + 5 * ZB + 2 * SB);
  unsigned short* S3   = (unsigned short*)(ws + 5 * ZB + 3 * SB);
  unsigned short* Wk2  = (unsigned short*)(ws + 5 * ZB + 4 * SB);

  k_cvt_st<<<dim3(64), dim3(256), 0, stream>>>(S, Sbf, SbfT);
  k_cvt_w<<<dim3(256), dim3(256), 0, stream>>>(W, Wk2);
  k_cvt_x<<<dim3(1024), dim3(256), 0, stream>>>(X, Xbf, Xt);

  gemm_s<<<dim3(64), dim3(256), 0, stream>>>(Sbf, SbfT, S2);   // S^2
  gemm_s<<<dim3(64), dim3(256), 0, stream>>>(S2, SbfT, S3);    // S^3

  hipFuncSetAttribute((const void*)k_chain8,
                      hipFuncAttributeMaxDynamicSharedMemorySize, 131072);
  k_chain8<<<dim3(768), dim3(512), 131072, stream>>>(Xt, Sbf, S2, S3, Zn1, Zn2, Zn3);

  k_out<<<dim3(1024), dim3(256), 0, stream>>>(Xbf, Zn1, Zn2, Zn3, Wk2, bvec, Y);
}